// Round 5
// baseline (786.689 us; speedup 1.0000x reference)
//
#include <hip/hip_runtime.h>

// DynamicFilterLayer2D: out[b,c,h,w] = sum_{i,j in 3x3} xpad[b,c,h+i-1,w+j-1] * f[b,c,i*3+j,h,w]
// B=8, C=32, H=256, W=256, K=3, PAD=1. All float32.
// Memory-bound: ~805 MB total traffic -> roofline ~128 us @ 6.3 TB/s. Prior session's
// 2-row/thread version measured 789.8 us (~1.0 TB/s). Theory: latency-bound, two causes:
//  (1) occupancy capped ~2 waves/SIMD by ~150+ VGPR (18 in-flight filter v4f),
//  (2) s_waitcnt vmcnt(0) before the halo shuffles if the compiler doesn't hoist
//      filter loads above the x-load wait -> full HBM latency exposed per wave.
// This version: ONE output row per thread + EXPLICIT issue order:
//  - issue 3 x-row loads, then ALL 9 filter loads (12 VMEM in flight / thread),
//    THEN shuffles (wait = vmcnt(9), filters still flying), then FMA drain.
//  - ~75-95 VGPR -> launch_bounds(256,4) with no spill risk; 4.2M threads for TLP.
//  - x re-read 3x (vs 2x before), but x (64 MiB) is L3-resident -> HBM bytes ~unchanged.
//  - halo columns via __shfl from neighbor lanes (lane 0/63 edges == zero-pad).
//  - nontemporal loads for filters, nontemporal store for out (single-use streams).
// NOTE: __builtin_nontemporal_* requires a native clang vector type, not HIP's float4 struct.

typedef float v4f __attribute__((ext_vector_type(4)));

constexpr int Bc = 8;
constexpr int Cc = 32;
constexpr int Hc = 256;
constexpr int Wc = 256;
constexpr int HW = Hc * Wc;
constexpr int W4 = Wc / 4;   // 64

__global__ __launch_bounds__(256, 4) void dyn_filter_kernel(
    const float* __restrict__ x,
    const float* __restrict__ f,
    float* __restrict__ out)
{
    int idx  = blockIdx.x * blockDim.x + threadIdx.x;
    int lane = threadIdx.x & 63;

    int w4 = idx & (W4 - 1);      // == lane (blockDim is a multiple of 64)
    int t  = idx >> 6;
    int h  = t & (Hc - 1);        // output row
    int bc = t >> 8;              // fused b*C+c plane index, [0, 256)
    int w0 = w4 << 2;

    // ---- 1) issue 3 x-row loads (h-1 .. h+1); zero for out-of-range (wave-uniform) ----
    const float* xrowbase = x + (size_t)bc * HW + w0;
    v4f r[3];
#pragma unroll
    for (int k = 0; k < 3; ++k) {
        int hy = h - 1 + k;
        if (hy >= 0 && hy < Hc)
            r[k] = *(const v4f*)(xrowbase + (size_t)hy * Wc);
        else
            r[k] = (v4f)(0.f);
    }

    // ---- 2) issue ALL 9 filter loads before any wait (max MLP) ----
    const float* fbase = f + (size_t)bc * 9 * HW + (size_t)h * Wc + w0;
    v4f fv[9];
#pragma unroll
    for (int kk = 0; kk < 9; ++kk)
        fv[kk] = __builtin_nontemporal_load((const v4f*)(fbase + (size_t)kk * HW));

    // ---- 3) column halos via shuffle (waits only on the 3 x loads, filters in flight) ----
    float lft[3], rgt[3];
#pragma unroll
    for (int k = 0; k < 3; ++k) {
        lft[k] = __shfl_up(r[k].w, 1);
        rgt[k] = __shfl_down(r[k].x, 1);
        if (lane == 0)  lft[k] = 0.f;   // zero pad at w = -1
        if (lane == 63) rgt[k] = 0.f;   // zero pad at w = 256
    }

    // ---- 4) FMA drain, consuming filters in issue order ----
    v4f acc = (v4f)(0.f);
#pragma unroll
    for (int di = 0; di < 3; ++di) {
        v4f   xa = r[di];
        float la = lft[di];
        float ra = rgt[di];
#pragma unroll
        for (int dj = 0; dj < 3; ++dj) {
            v4f wa;
            if (dj == 0) {        // window cols w-1..w+2
                wa = (v4f){la,   xa.x, xa.y, xa.z};
            } else if (dj == 1) { // centered
                wa = xa;
            } else {              // window cols w+1..w+4
                wa = (v4f){xa.y, xa.z, xa.w, ra};
            }
            acc += wa * fv[di * 3 + dj];
        }
    }

    float* op = out + (size_t)bc * HW + (size_t)h * Wc + w0;
    __builtin_nontemporal_store(acc, (v4f*)op);
}

extern "C" void kernel_launch(void* const* d_in, const int* in_sizes, int n_in,
                              void* d_out, int out_size, void* d_ws, size_t ws_size,
                              hipStream_t stream) {
    const float* x = (const float*)d_in[0];
    const float* f = (const float*)d_in[1];
    float* out = (float*)d_out;

    int total = Bc * Cc * Hc * W4;           // 4,194,304 threads
    int block = 256;
    int grid  = (total + block - 1) / block; // 16384 blocks
    dyn_filter_kernel<<<grid, block, 0, stream>>>(x, f, out);
}